// Round 15
// baseline (494.133 us; speedup 1.0000x reference)
//
#include <hip/hip_runtime.h>

#define NODES 100000
#define NEDGE 1600000
#define NREL  3
#define DIN   128
#define DHID  128
#define DOUT  64

#define NBUCK 782      // ceil(NODES/128), bucket = 128 nodes
#define CHUNK 6144     // edges per block in partition
#define NBLK  261      // ceil(NEDGE/CHUNK)
#define SEGCAP 8192    // fixed per-bucket capacity (mean 6144, sigma 78 -> +26 sigma)

typedef unsigned short ushort_t;
typedef __attribute__((ext_vector_type(8))) short bf16x8;
typedef __attribute__((ext_vector_type(4))) float f32x4;

__device__ __forceinline__ unsigned f2bf1(float f) {
    unsigned u = __float_as_uint(f);
    return (u + 0x7fffu + ((u >> 16) & 1u)) >> 16;   // RTNE f32->bf16
}

// ---------------------------------------------------------------------------
// block-wide exclusive scan helper over NBUCK LDS counters (256 threads)
__device__ __forceinline__ void scan_nbuck(unsigned* hist, unsigned* loff,
                                           unsigned* wred, int tid) {
    const int lane = tid & 63, wid = tid >> 6;
    unsigned s4[4];
    unsigned tsum = 0;
    const int sbase = tid * 4;
#pragma unroll
    for (int j = 0; j < 4; j++) {
        const unsigned c = (sbase + j < NBUCK) ? hist[sbase + j] : 0u;
        s4[j] = tsum;
        tsum += c;
    }
    unsigned incl = tsum;
    for (int o = 1; o < 64; o <<= 1) {
        const unsigned t = __shfl_up(incl, o, 64);
        if (lane >= o) incl += t;
    }
    if (lane == 63) wred[wid] = incl;
    __syncthreads();
    if (tid == 0) {
        unsigned a = 0;
        for (int w = 0; w < 4; w++) { const unsigned t = wred[w]; wred[w] = a; a += t; }
    }
    __syncthreads();
    const unsigned texcl = wred[wid] + incl - tsum;
#pragma unroll
    for (int j = 0; j < 4; j++)
        if (sbase + j < NBUCK) loff[sbase + j] = texcl + s4[j];
    __syncthreads();
}

// ---------------------------------------------------------------------------
// fused partition, single histogram pass for BOTH keys:
// pass1 reads src+dst once -> histD + histS; scan both; reserve both;
// pass2a/3a: dst-sorted u32 runs -> inter32; pass2b/3b: src-sorted u16 -> inter16.
__global__ __launch_bounds__(256) void partition_kernel(
    const int* __restrict__ edges, int* __restrict__ bcurD,
    int* __restrict__ bcurS, unsigned* __restrict__ inter32,
    ushort_t* __restrict__ inter16) {
    __shared__ unsigned histD[NBUCK], histS[NBUCK];
    __shared__ unsigned loffD[NBUCK], loffS[NBUCK];
    __shared__ unsigned resvD[NBUCK], resvS[NBUCK];
    __shared__ unsigned sorted[CHUNK];
    __shared__ ushort_t bof[CHUNK];
    __shared__ unsigned wred[4];
    const int tid = threadIdx.x;
    const int r = blockIdx.y;
    const int e0 = blockIdx.x * CHUNK;
    const int e1 = min(e0 + CHUNK, NEDGE);
    const int len = e1 - e0;
    const int* __restrict__ src = edges + (size_t)r * 2 * NEDGE;
    const int* __restrict__ dst = src + NEDGE;

    for (int i = tid; i < NBUCK; i += 256) { histD[i] = 0; histS[i] = 0; }
    __syncthreads();
    // pass 1: both histograms from one edge read
    for (int e = e0 + tid; e < e1; e += 256) {
        atomicAdd(&histD[dst[e] >> 7], 1u);
        atomicAdd(&histS[src[e] >> 7], 1u);
    }
    __syncthreads();
    scan_nbuck(histD, loffD, wred, tid);
    scan_nbuck(histS, loffS, wred, tid);
    // reserve global runs for both; reset hists to rank cursors
    for (int i = tid; i < NBUCK; i += 256) {
        const unsigned cD = histD[i];
        resvD[i] = cD ? (unsigned)atomicAdd(&bcurD[i], (int)cD) : 0u;
        histD[i] = 0;
        const unsigned cS = histS[i];
        resvS[i] = cS ? (unsigned)atomicAdd(&bcurS[i], (int)cS) : 0u;
        histS[i] = 0;
    }
    __syncthreads();
    // pass 2a: place dst-sorted in LDS
    for (int e = e0 + tid; e < e1; e += 256) {
        const int d = dst[e];
        const int b = d >> 7;
        const unsigned rank = atomicAdd(&histD[b], 1u);
        const unsigned pos = loffD[b] + rank;
        sorted[pos] = ((unsigned)(d & 127) << 19) | (unsigned)(r * NODES + src[e]);
        bof[pos] = (ushort_t)b;
    }
    __syncthreads();
    // pass 3a: coalesced run writes
    for (int i = tid; i < len; i += 256) {
        const int b = bof[i];
        inter32[(size_t)b * SEGCAP + resvD[b] + ((unsigned)i - loffD[b])] = sorted[i];
    }
    __syncthreads();
    // pass 2b: place src-sorted (bucket packed in word)
    for (int e = e0 + tid; e < e1; e += 256) {
        const int s = src[e];
        const int b = s >> 7;
        const unsigned rank = atomicAdd(&histS[b], 1u);
        sorted[loffS[b] + rank] =
            ((unsigned)b << 9) | ((unsigned)r << 7) | (unsigned)(s & 127);
    }
    __syncthreads();
    // pass 3b: coalesced run writes
    for (int i = tid; i < len; i += 256) {
        const unsigned w = sorted[i];
        const int b = w >> 9;
        inter16[(size_t)b * SEGCAP + resvS[b] + ((unsigned)i - loffS[b])] =
            (ushort_t)(w & 0x1ffu);
    }
}

// ---------------------------------------------------------------------------
// fused build: inlined bucket-base scan + dst-CSR (rel-grouped) + rowptr/
// rel01/rin, then src-deg -> rout. bscan kernel eliminated.
__global__ __launch_bounds__(256) void build_kernel(
    const unsigned* __restrict__ inter32, const int* __restrict__ bcurD,
    const ushort_t* __restrict__ inter16, const int* __restrict__ bcurS,
    int* __restrict__ csr, int* __restrict__ rowptr, unsigned* __restrict__ rel01,
    float* __restrict__ rin, float* __restrict__ rout) {
    __shared__ unsigned hist[NBUCK];
    __shared__ unsigned loff[NBUCK];
    __shared__ unsigned wred[4];
    __shared__ int degR[NREL][128];
    __shared__ int rp[129];
    __shared__ int cur3[NREL][128];
    __shared__ int csr_lds[SEGCAP];
    const int b = blockIdx.x;
    const int tid = threadIdx.x;
    const int n0 = b << 7;
    const int nn = min(128, NODES - n0);

    // inlined exclusive scan of bcurD -> bucket bases
    for (int i = tid; i < NBUCK; i += 256) hist[i] = (unsigned)bcurD[i];
    for (int i = tid; i < NREL * 128; i += 256) ((int*)degR)[i] = 0;
    __syncthreads();
    scan_nbuck(hist, loff, wred, tid);
    const int s0 = (int)loff[b];
    const int len = bcurD[b];
    const int s1 = s0 + len;
    const unsigned* __restrict__ seg = inter32 + (size_t)b * SEGCAP;

    for (int s = tid; s < len; s += 256) {
        const unsigned w = seg[s];
        const int dl = w >> 19;
        const int p = (int)(w & 0x7FFFFu);
        const int rel = p < NODES ? 0 : (p < 2 * NODES ? 1 : 2);
        atomicAdd(&degR[rel][dl], 1);
    }
    __syncthreads();
    if (tid == 0) {
        int a = 0;
        for (int i = 0; i < 128; i++) {
            rp[i] = a;
            a += degR[0][i] + degR[1][i] + degR[2][i];
        }
        rp[128] = a;
    }
    __syncthreads();
    if (tid < 128) {
        const int c0 = rp[tid];
        cur3[0][tid] = c0;
        cur3[1][tid] = c0 + degR[0][tid];
        cur3[2][tid] = c0 + degR[0][tid] + degR[1][tid];
    }
    if (tid < nn) {
        const int node = n0 + tid;
        rowptr[node] = s0 + rp[tid];
        rel01[node] = (unsigned)degR[0][tid] | ((unsigned)degR[1][tid] << 16);
#pragma unroll
        for (int r = 0; r < NREL; r++) {
            const int d = degR[r][tid];
            rin[r * NODES + node] = rsqrtf((float)(d ? d : 1));
        }
    }
    if (b == NBUCK - 1 && tid == 0) rowptr[NODES] = s1;
    __syncthreads();
    for (int s = tid; s < len; s += 256) {
        const unsigned w = seg[s];
        const int dl = w >> 19;
        const int p = (int)(w & 0x7FFFFu);
        const int rel = p < NODES ? 0 : (p < 2 * NODES ? 1 : 2);
        const int srcn = p - rel * NODES;
        const int slot = atomicAdd(&cur3[rel][dl], 1);
        csr_lds[slot] = srcn;
    }
    __syncthreads();
    for (int i = tid; i < len; i += 256) csr[s0 + i] = csr_lds[i];

    // ---- src-degree phase -> rout
    __syncthreads();
    for (int i = tid; i < NREL * 128; i += 256) ((int*)degR)[i] = 0;
    __syncthreads();
    const int len2 = bcurS[b];
    const ushort_t* __restrict__ seg16 = inter16 + (size_t)b * SEGCAP;
    for (int s = tid; s < len2; s += 256) {
        const unsigned p = seg16[s];
        atomicAdd(&degR[p >> 7][p & 127], 1);
    }
    __syncthreads();
    if (tid < nn) {
        const int node = n0 + tid;
#pragma unroll
        for (int r = 0; r < NREL; r++) {
            const int d = degR[r][tid];
            rout[r * NODES + node] = rsqrtf((float)(d ? d : 1));
        }
    }
}

// ---------------------------------------------------------------------------
// fused 3-relation MFMA GEMM: m_all[r][row][c] = rout_r[row]*(A@W_r)[row][c]
// A staged once (f32->bf16 for layer 1, bf16 for layer 2); W_r staged per rel.
template <int ODIM, bool IN_F32>
__global__ __launch_bounds__(256) void gemm_fused(
    const void* __restrict__ A, const float* __restrict__ rout_all,
    const float* __restrict__ W_all, ushort_t* __restrict__ m_all) {
    constexpr int PAD = DIN + 8;
    constexpr int NT = ODIM / 16;
    __shared__ ushort_t Al[64 * PAD];
    __shared__ ushort_t Wt[ODIM * PAD];
    const int tid = threadIdx.x;
    const int row0 = blockIdx.x * 64;

    for (int idx = tid * 8; idx < 64 * DIN; idx += 2048) {
        const int rr = idx >> 7, kk = idx & 127;
        const int row = row0 + rr;
        uint4 p = make_uint4(0u, 0u, 0u, 0u);
        if (row < NODES) {
            if (IN_F32) {
                const float* Af = (const float*)A + (size_t)row * DIN + kk;
                const float4 a = *(const float4*)Af;
                const float4 b = *(const float4*)(Af + 4);
                p.x = f2bf1(a.x) | (f2bf1(a.y) << 16);
                p.y = f2bf1(a.z) | (f2bf1(a.w) << 16);
                p.z = f2bf1(b.x) | (f2bf1(b.y) << 16);
                p.w = f2bf1(b.z) | (f2bf1(b.w) << 16);
            } else {
                p = *(const uint4*)((const ushort_t*)A + (size_t)row * DIN + kk);
            }
        }
        *(uint4*)(Al + rr * PAD + kk) = p;
    }

    const int l = tid & 63, wv = tid >> 6, lr = l & 15, lg = l >> 4;
    for (int r = 0; r < NREL; r++) {
        __syncthreads();   // Al ready (r=0) / prev-rel Wt readers done (r>0)
        const float* __restrict__ W = W_all + (size_t)r * DIN * ODIM;
        for (int idx = tid; idx < ODIM * (DIN / 8); idx += 256) {
            const int c = idx % ODIM, kh = idx / ODIM;
            unsigned pk[4];
#pragma unroll
            for (int j = 0; j < 4; j++) {
                const float lo = W[(size_t)(kh * 8 + 2 * j) * ODIM + c];
                const float hi = W[(size_t)(kh * 8 + 2 * j + 1) * ODIM + c];
                pk[j] = f2bf1(lo) | (f2bf1(hi) << 16);
            }
            *(uint4*)(Wt + c * PAD + kh * 8) = *(const uint4*)pk;
        }
        __syncthreads();

        f32x4 acc[NT];
#pragma unroll
        for (int j = 0; j < NT; j++) acc[j] = (f32x4){0.f, 0.f, 0.f, 0.f};
        const ushort_t* ap = Al + (wv * 16 + lr) * PAD + lg * 8;
        const ushort_t* bp = Wt + lr * PAD + lg * 8;
#pragma unroll
        for (int ks = 0; ks < DIN; ks += 32) {
            const bf16x8 af = *(const bf16x8*)(ap + ks);
#pragma unroll
            for (int j = 0; j < NT; j++) {
                const bf16x8 bfr = *(const bf16x8*)(bp + (size_t)j * 16 * PAD + ks);
                acc[j] = __builtin_amdgcn_mfma_f32_16x16x32_bf16(af, bfr, acc[j], 0, 0, 0);
            }
        }

        const float* __restrict__ rout = rout_all + (size_t)r * NODES;
        ushort_t* __restrict__ mout = m_all + (size_t)r * NODES * ODIM;
        const int orow0 = row0 + wv * 16 + lg * 4;
#pragma unroll
        for (int rg = 0; rg < 4; rg++) {
            const int row = orow0 + rg;
            if (row < NODES) {
                const float sc = rout[row];
#pragma unroll
                for (int j = 0; j < NT; j++)
                    mout[(size_t)row * ODIM + j * 16 + lr] =
                        (ushort_t)f2bf1(acc[j][rg] * sc);
            }
        }
    }
}

// ---------------------------------------------------------------------------
// pull-agg, rel-grouped CSR: 16 threads/node, 8 (or 4) cols each, uint4 gathers.
template <int ODIM, bool L1>
__global__ __launch_bounds__(256) void agg_kernel(
    const ushort_t* __restrict__ m_all, const int* __restrict__ rowptr,
    const unsigned* __restrict__ rel01, const int* __restrict__ csr,
    const float* __restrict__ rin, const float* __restrict__ bias,
    float* __restrict__ outf, ushort_t* __restrict__ outh) {
    constexpr int CPT = ODIM / 16;   // 8 (128) or 4 (64) cols per thread
    const int v = blockIdx.x * 16 + (threadIdx.x >> 4);
    const int colbase = (threadIdx.x & 15) * CPT;
    const int b = rowptr[v];
    const int e2 = rowptr[v + 1];
    const unsigned c01 = rel01[v];
    const int cnt0 = (int)(c01 & 0xffffu);
    const int cnt1 = (int)(c01 >> 16);

    float acc[CPT];
#pragma unroll
    for (int j = 0; j < CPT; j++) acc[j] = 0.f;

    const ushort_t* mr = m_all + colbase;
    int beg = b;
#pragma unroll
    for (int r = 0; r < NREL; r++) {
        const int end = (r == 0) ? b + cnt0 : (r == 1) ? b + cnt0 + cnt1 : e2;
        float s[CPT];
#pragma unroll
        for (int j = 0; j < CPT; j++) s[j] = 0.f;
#pragma unroll 4
        for (int i = beg; i < end; i++) {
            const unsigned off = (unsigned)csr[i] * ODIM;
            if constexpr (CPT == 8) {
                const uint4 p = *(const uint4*)(mr + off);
                s[0] += __uint_as_float(p.x << 16);
                s[1] += __uint_as_float(p.x & 0xffff0000u);
                s[2] += __uint_as_float(p.y << 16);
                s[3] += __uint_as_float(p.y & 0xffff0000u);
                s[4] += __uint_as_float(p.z << 16);
                s[5] += __uint_as_float(p.z & 0xffff0000u);
                s[6] += __uint_as_float(p.w << 16);
                s[7] += __uint_as_float(p.w & 0xffff0000u);
            } else {
                const uint2 p = *(const uint2*)(mr + off);
                s[0] += __uint_as_float(p.x << 16);
                s[1] += __uint_as_float(p.x & 0xffff0000u);
                s[2] += __uint_as_float(p.y << 16);
                s[3] += __uint_as_float(p.y & 0xffff0000u);
            }
        }
        const float sc = rin[r * NODES + v];
#pragma unroll
        for (int j = 0; j < CPT; j++) acc[j] = fmaf(s[j], sc, acc[j]);
        beg = end;
        mr += (size_t)NODES * ODIM;
    }

    if (L1) {
        unsigned pk[CPT / 2];
#pragma unroll
        for (int j = 0; j < CPT; j += 2) {
            const int c0 = colbase + j, c1 = colbase + j + 1;
            const float v0 = fmaxf(acc[j] + bias[c0] + bias[ODIM + c0] + bias[2 * ODIM + c0], 0.f);
            const float v1 = fmaxf(acc[j + 1] + bias[c1] + bias[ODIM + c1] + bias[2 * ODIM + c1], 0.f);
            pk[j / 2] = f2bf1(v0) | (f2bf1(v1) << 16);
        }
        *(uint4*)(outh + (size_t)v * ODIM + colbase) = *(const uint4*)pk;
    } else {
        float o[CPT];
#pragma unroll
        for (int j = 0; j < CPT; j++) {
            const int c = colbase + j;
            o[j] = acc[j] + bias[c] + bias[ODIM + c] + bias[2 * ODIM + c];
        }
        *(float4*)(outf + (size_t)v * ODIM + colbase) = *(const float4*)o;
    }
}

// ---------------------------------------------------------------------------
extern "C" void kernel_launch(void* const* d_in, const int* in_sizes, int n_in,
                              void* d_out, int out_size, void* d_ws, size_t ws_size,
                              hipStream_t stream) {
    const float* x  = (const float*)d_in[0];
    const int* edges = (const int*)d_in[1];
    const float* W1 = (const float*)d_in[2];
    const float* b1 = (const float*)d_in[3];
    const float* W2 = (const float*)d_in[4];
    const float* b2 = (const float*)d_in[5];
    float* out = (float*)d_out;

    char* ws = (char*)d_ws;
    size_t off = 0;
    auto alloc = [&](size_t bytes) {
        void* p = ws + off;
        off = (off + bytes + 255) & ~(size_t)255;
        return p;
    };
    float*    rout   = (float*)alloc((size_t)NREL * NODES * 4);        // 1.2 MB
    float*    rin    = (float*)alloc((size_t)NREL * NODES * 4);        // 1.2 MB
    int*      bcur   = (int*)alloc((size_t)2 * NBUCK * 4);             // dst + src cursors
    int*      bcurS  = bcur + NBUCK;
    int*      rowptr = (int*)alloc((size_t)(NODES + 1) * 4);
    unsigned* rel01  = (unsigned*)alloc((size_t)NODES * 4);
    int*      csr    = (int*)alloc((size_t)NREL * NEDGE * 4);             // 19.2 MB
    ushort_t* m_all  = (ushort_t*)alloc((size_t)NREL * NODES * DHID * 2); // 76.8 MB
    ushort_t* h      = (ushort_t*)alloc((size_t)NODES * DHID * 2);        // 25.6 MB
    // overlays on m_all (dead before gemm writes): dst-sorted u32 + src-sorted u16
    unsigned* inter32 = (unsigned*)m_all;                                 // 25.6 MB
    ushort_t* inter16 = (ushort_t*)((char*)m_all + (size_t)NBUCK * SEGCAP * 4); // 12.8 MB

    // --- CSR + degree build: one fused partition + one fused build ---
    hipMemsetAsync(bcur, 0, (size_t)2 * NBUCK * 4, stream);
    partition_kernel<<<dim3(NBLK, NREL), 256, 0, stream>>>(
        edges, bcur, bcurS, inter32, inter16);
    build_kernel<<<NBUCK, 256, 0, stream>>>(
        inter32, bcur, inter16, bcurS, csr, rowptr, rel01, rin, rout);

    // --- layer 1: fused 3-rel GEMM (x f32 staged once) + combined agg ---
    gemm_fused<DHID, true><<<(NODES + 63) / 64, 256, 0, stream>>>(
        x, rout, W1, m_all);
    agg_kernel<DHID, true><<<NODES / 16, 256, 0, stream>>>(
        m_all, rowptr, rel01, csr, rin, b1, nullptr, h);

    // --- layer 2: fused 3-rel GEMM (h bf16 staged once) + combined agg ---
    gemm_fused<DOUT, false><<<(NODES + 63) / 64, 256, 0, stream>>>(
        h, rout, W2, m_all);
    agg_kernel<DOUT, false><<<NODES / 16, 256, 0, stream>>>(
        m_all, rowptr, rel01, csr, rin, b2, out, nullptr);
}

// Round 16
// 478.230 us; speedup vs baseline: 1.0333x; 1.0333x over previous
//
#include <hip/hip_runtime.h>

#define NODES 100000
#define NEDGE 1600000
#define NREL  3
#define DIN   128
#define DHID  128
#define DOUT  64

#define NBUCK 782      // ceil(NODES/128), bucket = 128 nodes
#define CHUNK 6144     // edges per block in partition
#define NBLK  261      // ceil(NEDGE/CHUNK)
#define SEGCAP 8192    // fixed per-bucket capacity (mean 6144, sigma 78 -> +26 sigma)

typedef unsigned short ushort_t;
typedef __attribute__((ext_vector_type(8))) short bf16x8;
typedef __attribute__((ext_vector_type(4))) float f32x4;

__device__ __forceinline__ unsigned f2bf1(float f) {
    unsigned u = __float_as_uint(f);
    return (u + 0x7fffu + ((u >> 16) & 1u)) >> 16;   // RTNE f32->bf16
}

// ---------------------------------------------------------------------------
// block-wide exclusive scan helper over NBUCK LDS counters (256 threads)
__device__ __forceinline__ void scan_nbuck(unsigned* hist, unsigned* loff,
                                           unsigned* wred, int tid) {
    const int lane = tid & 63, wid = tid >> 6;
    unsigned s4[4];
    unsigned tsum = 0;
    const int sbase = tid * 4;
#pragma unroll
    for (int j = 0; j < 4; j++) {
        const unsigned c = (sbase + j < NBUCK) ? hist[sbase + j] : 0u;
        s4[j] = tsum;
        tsum += c;
    }
    unsigned incl = tsum;
    for (int o = 1; o < 64; o <<= 1) {
        const unsigned t = __shfl_up(incl, o, 64);
        if (lane >= o) incl += t;
    }
    if (lane == 63) wred[wid] = incl;
    __syncthreads();
    if (tid == 0) {
        unsigned a = 0;
        for (int w = 0; w < 4; w++) { const unsigned t = wred[w]; wred[w] = a; a += t; }
    }
    __syncthreads();
    const unsigned texcl = wred[wid] + incl - tsum;
#pragma unroll
    for (int j = 0; j < 4; j++)
        if (sbase + j < NBUCK) loff[sbase + j] = texcl + s4[j];
    __syncthreads();
}

// ---------------------------------------------------------------------------
// fused partition: one edge read, two sequential LDS counting sorts.
// Phase A (dst): inter32[b] <- (dst&127)<<19 | rel*N+src, coalesced runs.
// Phase B (src): inter16[b] <- rel<<7 | src&127.
__global__ __launch_bounds__(256) void partition_kernel(
    const int* __restrict__ edges, int* __restrict__ bcurD,
    int* __restrict__ bcurS, unsigned* __restrict__ inter32,
    ushort_t* __restrict__ inter16) {
    __shared__ unsigned hist[NBUCK];
    __shared__ unsigned loff[NBUCK];
    __shared__ unsigned resv[NBUCK];
    __shared__ unsigned sorted[CHUNK];
    __shared__ ushort_t bof[CHUNK];
    __shared__ unsigned wred[4];
    const int tid = threadIdx.x;
    const int r = blockIdx.y;
    const int e0 = blockIdx.x * CHUNK;
    const int e1 = min(e0 + CHUNK, NEDGE);
    const int len = e1 - e0;
    const int* __restrict__ src = edges + (size_t)r * 2 * NEDGE;
    const int* __restrict__ dst = src + NEDGE;

    // ---- phase A: dst-keyed sort -> inter32
    for (int i = tid; i < NBUCK; i += 256) hist[i] = 0;
    __syncthreads();
    for (int e = e0 + tid; e < e1; e += 256)
        atomicAdd(&hist[dst[e] >> 7], 1u);
    __syncthreads();
    scan_nbuck(hist, loff, wred, tid);
    for (int i = tid; i < NBUCK; i += 256) {
        const unsigned c = hist[i];
        resv[i] = c ? (unsigned)atomicAdd(&bcurD[i], (int)c) : 0u;
        hist[i] = 0;
    }
    __syncthreads();
    for (int e = e0 + tid; e < e1; e += 256) {
        const int d = dst[e];
        const int b = d >> 7;
        const unsigned rank = atomicAdd(&hist[b], 1u);
        const unsigned pos = loff[b] + rank;
        sorted[pos] = ((unsigned)(d & 127) << 19) | (unsigned)(r * NODES + src[e]);
        bof[pos] = (ushort_t)b;
    }
    __syncthreads();
    for (int i = tid; i < len; i += 256) {
        const int b = bof[i];
        inter32[(size_t)b * SEGCAP + resv[b] + ((unsigned)i - loff[b])] = sorted[i];
    }
    __syncthreads();

    // ---- phase B: src-keyed sort -> inter16 (bucket packed in word, no bof)
    for (int i = tid; i < NBUCK; i += 256) hist[i] = 0;
    __syncthreads();
    for (int e = e0 + tid; e < e1; e += 256)
        atomicAdd(&hist[src[e] >> 7], 1u);
    __syncthreads();
    scan_nbuck(hist, loff, wred, tid);
    for (int i = tid; i < NBUCK; i += 256) {
        const unsigned c = hist[i];
        resv[i] = c ? (unsigned)atomicAdd(&bcurS[i], (int)c) : 0u;
        hist[i] = 0;
    }
    __syncthreads();
    for (int e = e0 + tid; e < e1; e += 256) {
        const int s = src[e];
        const int b = s >> 7;
        const unsigned rank = atomicAdd(&hist[b], 1u);
        sorted[loff[b] + rank] =
            ((unsigned)b << 9) | ((unsigned)r << 7) | (unsigned)(s & 127);
    }
    __syncthreads();
    for (int i = tid; i < len; i += 256) {
        const unsigned w = sorted[i];
        const int b = w >> 9;
        inter16[(size_t)b * SEGCAP + resv[b] + ((unsigned)i - loff[b])] =
            (ushort_t)(w & 0x1ffu);
    }
}

// scan 782 dst-bucket counts -> bucketBase[783]
__global__ __launch_bounds__(1024) void bscan_kernel(
    const int* __restrict__ bcur, int* __restrict__ bucketBase) {
    __shared__ int wsum[16];
    const int tid = threadIdx.x, lane = tid & 63, wid = tid >> 6;
    const int v = (tid < NBUCK) ? bcur[tid] : 0;
    int incl = v;
    for (int off = 1; off < 64; off <<= 1) {
        const int t = __shfl_up(incl, off, 64);
        if (lane >= off) incl += t;
    }
    if (lane == 63) wsum[wid] = incl;
    __syncthreads();
    if (tid == 0) {
        int a = 0;
        for (int w = 0; w < 16; w++) { const int t = wsum[w]; wsum[w] = a; a += t; }
    }
    __syncthreads();
    const int excl = wsum[wid] + incl - v;
    if (tid <= NBUCK) bucketBase[tid] = excl;
}

// ---------------------------------------------------------------------------
// fused build: dst-CSR (rel-grouped) + rowptr/rel01/rin, then src-deg -> rout
__global__ __launch_bounds__(256) void build_kernel(
    const unsigned* __restrict__ inter32, const int* __restrict__ bucketBase,
    const ushort_t* __restrict__ inter16, const int* __restrict__ bcurS,
    int* __restrict__ csr, int* __restrict__ rowptr, unsigned* __restrict__ rel01,
    float* __restrict__ rin, float* __restrict__ rout) {
    __shared__ int degR[NREL][128];
    __shared__ int rp[129];
    __shared__ int cur3[NREL][128];
    __shared__ int csr_lds[SEGCAP];
    const int b = blockIdx.x;
    const int tid = threadIdx.x;
    const int n0 = b << 7;
    const int nn = min(128, NODES - n0);
    const int s0 = bucketBase[b], s1 = bucketBase[b + 1];
    const int len = s1 - s0;
    const unsigned* __restrict__ seg = inter32 + (size_t)b * SEGCAP;

    for (int i = tid; i < NREL * 128; i += 256) ((int*)degR)[i] = 0;
    __syncthreads();
    for (int s = tid; s < len; s += 256) {
        const unsigned w = seg[s];
        const int dl = w >> 19;
        const int p = (int)(w & 0x7FFFFu);
        const int rel = p < NODES ? 0 : (p < 2 * NODES ? 1 : 2);
        atomicAdd(&degR[rel][dl], 1);
    }
    __syncthreads();
    if (tid == 0) {
        int a = 0;
        for (int i = 0; i < 128; i++) {
            rp[i] = a;
            a += degR[0][i] + degR[1][i] + degR[2][i];
        }
        rp[128] = a;
    }
    __syncthreads();
    if (tid < 128) {
        const int c0 = rp[tid];
        cur3[0][tid] = c0;
        cur3[1][tid] = c0 + degR[0][tid];
        cur3[2][tid] = c0 + degR[0][tid] + degR[1][tid];
    }
    if (tid < nn) {
        const int node = n0 + tid;
        rowptr[node] = s0 + rp[tid];
        rel01[node] = (unsigned)degR[0][tid] | ((unsigned)degR[1][tid] << 16);
#pragma unroll
        for (int r = 0; r < NREL; r++) {
            const int d = degR[r][tid];
            rin[r * NODES + node] = rsqrtf((float)(d ? d : 1));
        }
    }
    if (b == NBUCK - 1 && tid == 0) rowptr[NODES] = s1;
    __syncthreads();
    for (int s = tid; s < len; s += 256) {
        const unsigned w = seg[s];
        const int dl = w >> 19;
        const int p = (int)(w & 0x7FFFFu);
        const int rel = p < NODES ? 0 : (p < 2 * NODES ? 1 : 2);
        const int srcn = p - rel * NODES;
        const int slot = atomicAdd(&cur3[rel][dl], 1);
        csr_lds[slot] = srcn;
    }
    __syncthreads();
    for (int i = tid; i < len; i += 256) csr[s0 + i] = csr_lds[i];

    // ---- src-degree phase -> rout
    __syncthreads();
    for (int i = tid; i < NREL * 128; i += 256) ((int*)degR)[i] = 0;
    __syncthreads();
    const int len2 = bcurS[b];
    const ushort_t* __restrict__ seg16 = inter16 + (size_t)b * SEGCAP;
    for (int s = tid; s < len2; s += 256) {
        const unsigned p = seg16[s];
        atomicAdd(&degR[p >> 7][p & 127], 1);
    }
    __syncthreads();
    if (tid < nn) {
        const int node = n0 + tid;
#pragma unroll
        for (int r = 0; r < NREL; r++) {
            const int d = degR[r][tid];
            rout[r * NODES + node] = rsqrtf((float)(d ? d : 1));
        }
    }
}

// ---------------------------------------------------------------------------
// fused 3-relation MFMA GEMM: m_all[r][row][c] = rout_r[row]*(A@W_r)[row][c]
// A staged once (f32->bf16 for layer 1, bf16 for layer 2); W_r staged per rel.
template <int ODIM, bool IN_F32>
__global__ __launch_bounds__(256) void gemm_fused(
    const void* __restrict__ A, const float* __restrict__ rout_all,
    const float* __restrict__ W_all, ushort_t* __restrict__ m_all) {
    constexpr int PAD = DIN + 8;
    constexpr int NT = ODIM / 16;
    __shared__ ushort_t Al[64 * PAD];
    __shared__ ushort_t Wt[ODIM * PAD];
    const int tid = threadIdx.x;
    const int row0 = blockIdx.x * 64;

    for (int idx = tid * 8; idx < 64 * DIN; idx += 2048) {
        const int rr = idx >> 7, kk = idx & 127;
        const int row = row0 + rr;
        uint4 p = make_uint4(0u, 0u, 0u, 0u);
        if (row < NODES) {
            if (IN_F32) {
                const float* Af = (const float*)A + (size_t)row * DIN + kk;
                const float4 a = *(const float4*)Af;
                const float4 b = *(const float4*)(Af + 4);
                p.x = f2bf1(a.x) | (f2bf1(a.y) << 16);
                p.y = f2bf1(a.z) | (f2bf1(a.w) << 16);
                p.z = f2bf1(b.x) | (f2bf1(b.y) << 16);
                p.w = f2bf1(b.z) | (f2bf1(b.w) << 16);
            } else {
                p = *(const uint4*)((const ushort_t*)A + (size_t)row * DIN + kk);
            }
        }
        *(uint4*)(Al + rr * PAD + kk) = p;
    }

    const int l = tid & 63, wv = tid >> 6, lr = l & 15, lg = l >> 4;
    for (int r = 0; r < NREL; r++) {
        __syncthreads();   // Al ready (r=0) / prev-rel Wt readers done (r>0)
        const float* __restrict__ W = W_all + (size_t)r * DIN * ODIM;
        for (int idx = tid; idx < ODIM * (DIN / 8); idx += 256) {
            const int c = idx % ODIM, kh = idx / ODIM;
            unsigned pk[4];
#pragma unroll
            for (int j = 0; j < 4; j++) {
                const float lo = W[(size_t)(kh * 8 + 2 * j) * ODIM + c];
                const float hi = W[(size_t)(kh * 8 + 2 * j + 1) * ODIM + c];
                pk[j] = f2bf1(lo) | (f2bf1(hi) << 16);
            }
            *(uint4*)(Wt + c * PAD + kh * 8) = *(const uint4*)pk;
        }
        __syncthreads();

        f32x4 acc[NT];
#pragma unroll
        for (int j = 0; j < NT; j++) acc[j] = (f32x4){0.f, 0.f, 0.f, 0.f};
        const ushort_t* ap = Al + (wv * 16 + lr) * PAD + lg * 8;
        const ushort_t* bp = Wt + lr * PAD + lg * 8;
#pragma unroll
        for (int ks = 0; ks < DIN; ks += 32) {
            const bf16x8 af = *(const bf16x8*)(ap + ks);
#pragma unroll
            for (int j = 0; j < NT; j++) {
                const bf16x8 bfr = *(const bf16x8*)(bp + (size_t)j * 16 * PAD + ks);
                acc[j] = __builtin_amdgcn_mfma_f32_16x16x32_bf16(af, bfr, acc[j], 0, 0, 0);
            }
        }

        const float* __restrict__ rout = rout_all + (size_t)r * NODES;
        ushort_t* __restrict__ mout = m_all + (size_t)r * NODES * ODIM;
        const int orow0 = row0 + wv * 16 + lg * 4;
#pragma unroll
        for (int rg = 0; rg < 4; rg++) {
            const int row = orow0 + rg;
            if (row < NODES) {
                const float sc = rout[row];
#pragma unroll
                for (int j = 0; j < NT; j++)
                    mout[(size_t)row * ODIM + j * 16 + lr] =
                        (ushort_t)f2bf1(acc[j][rg] * sc);
            }
        }
    }
}

// ---------------------------------------------------------------------------
// pull-agg, rel-grouped CSR: 16 threads/node, 8 (or 4) cols each, uint4 gathers.
template <int ODIM, bool L1>
__global__ __launch_bounds__(256) void agg_kernel(
    const ushort_t* __restrict__ m_all, const int* __restrict__ rowptr,
    const unsigned* __restrict__ rel01, const int* __restrict__ csr,
    const float* __restrict__ rin, const float* __restrict__ bias,
    float* __restrict__ outf, ushort_t* __restrict__ outh) {
    constexpr int CPT = ODIM / 16;   // 8 (128) or 4 (64) cols per thread
    const int v = blockIdx.x * 16 + (threadIdx.x >> 4);
    const int colbase = (threadIdx.x & 15) * CPT;
    const int b = rowptr[v];
    const int e2 = rowptr[v + 1];
    const unsigned c01 = rel01[v];
    const int cnt0 = (int)(c01 & 0xffffu);
    const int cnt1 = (int)(c01 >> 16);

    float acc[CPT];
#pragma unroll
    for (int j = 0; j < CPT; j++) acc[j] = 0.f;

    const ushort_t* mr = m_all + colbase;
    int beg = b;
#pragma unroll
    for (int r = 0; r < NREL; r++) {
        const int end = (r == 0) ? b + cnt0 : (r == 1) ? b + cnt0 + cnt1 : e2;
        float s[CPT];
#pragma unroll
        for (int j = 0; j < CPT; j++) s[j] = 0.f;
#pragma unroll 4
        for (int i = beg; i < end; i++) {
            const unsigned off = (unsigned)csr[i] * ODIM;
            if constexpr (CPT == 8) {
                const uint4 p = *(const uint4*)(mr + off);
                s[0] += __uint_as_float(p.x << 16);
                s[1] += __uint_as_float(p.x & 0xffff0000u);
                s[2] += __uint_as_float(p.y << 16);
                s[3] += __uint_as_float(p.y & 0xffff0000u);
                s[4] += __uint_as_float(p.z << 16);
                s[5] += __uint_as_float(p.z & 0xffff0000u);
                s[6] += __uint_as_float(p.w << 16);
                s[7] += __uint_as_float(p.w & 0xffff0000u);
            } else {
                const uint2 p = *(const uint2*)(mr + off);
                s[0] += __uint_as_float(p.x << 16);
                s[1] += __uint_as_float(p.x & 0xffff0000u);
                s[2] += __uint_as_float(p.y << 16);
                s[3] += __uint_as_float(p.y & 0xffff0000u);
            }
        }
        const float sc = rin[r * NODES + v];
#pragma unroll
        for (int j = 0; j < CPT; j++) acc[j] = fmaf(s[j], sc, acc[j]);
        beg = end;
        mr += (size_t)NODES * ODIM;
    }

    if (L1) {
        unsigned pk[CPT / 2];
#pragma unroll
        for (int j = 0; j < CPT; j += 2) {
            const int c0 = colbase + j, c1 = colbase + j + 1;
            const float v0 = fmaxf(acc[j] + bias[c0] + bias[ODIM + c0] + bias[2 * ODIM + c0], 0.f);
            const float v1 = fmaxf(acc[j + 1] + bias[c1] + bias[ODIM + c1] + bias[2 * ODIM + c1], 0.f);
            pk[j / 2] = f2bf1(v0) | (f2bf1(v1) << 16);
        }
        *(uint4*)(outh + (size_t)v * ODIM + colbase) = *(const uint4*)pk;
    } else {
        float o[CPT];
#pragma unroll
        for (int j = 0; j < CPT; j++) {
            const int c = colbase + j;
            o[j] = acc[j] + bias[c] + bias[ODIM + c] + bias[2 * ODIM + c];
        }
        *(float4*)(outf + (size_t)v * ODIM + colbase) = *(const float4*)o;
    }
}

// ---------------------------------------------------------------------------
extern "C" void kernel_launch(void* const* d_in, const int* in_sizes, int n_in,
                              void* d_out, int out_size, void* d_ws, size_t ws_size,
                              hipStream_t stream) {
    const float* x  = (const float*)d_in[0];
    const int* edges = (const int*)d_in[1];
    const float* W1 = (const float*)d_in[2];
    const float* b1 = (const float*)d_in[3];
    const float* W2 = (const float*)d_in[4];
    const float* b2 = (const float*)d_in[5];
    float* out = (float*)d_out;

    char* ws = (char*)d_ws;
    size_t off = 0;
    auto alloc = [&](size_t bytes) {
        void* p = ws + off;
        off = (off + bytes + 255) & ~(size_t)255;
        return p;
    };
    float*    rout   = (float*)alloc((size_t)NREL * NODES * 4);        // 1.2 MB
    float*    rin    = (float*)alloc((size_t)NREL * NODES * 4);        // 1.2 MB
    int*      bcur   = (int*)alloc((size_t)2 * NBUCK * 4);             // dst + src cursors
    int*      bcurS  = bcur + NBUCK;
    int*      bbase  = (int*)alloc((size_t)(NBUCK + 1) * 4);
    int*      rowptr = (int*)alloc((size_t)(NODES + 1) * 4);
    unsigned* rel01  = (unsigned*)alloc((size_t)NODES * 4);
    int*      csr    = (int*)alloc((size_t)NREL * NEDGE * 4);             // 19.2 MB
    ushort_t* m_all  = (ushort_t*)alloc((size_t)NREL * NODES * DHID * 2); // 76.8 MB
    ushort_t* h      = (ushort_t*)alloc((size_t)NODES * DHID * 2);        // 25.6 MB
    // overlays on m_all (dead before gemm writes): dst-sorted u32 + src-sorted u16
    unsigned* inter32 = (unsigned*)m_all;                                 // 25.6 MB
    ushort_t* inter16 = (ushort_t*)((char*)m_all + (size_t)NBUCK * SEGCAP * 4); // 12.8 MB

    // --- CSR + degree build: one fused partition + one fused build ---
    hipMemsetAsync(bcur, 0, (size_t)2 * NBUCK * 4, stream);
    partition_kernel<<<dim3(NBLK, NREL), 256, 0, stream>>>(
        edges, bcur, bcurS, inter32, inter16);
    bscan_kernel<<<1, 1024, 0, stream>>>(bcur, bbase);
    build_kernel<<<NBUCK, 256, 0, stream>>>(
        inter32, bbase, inter16, bcurS, csr, rowptr, rel01, rin, rout);

    // --- layer 1: fused 3-rel GEMM (x f32 staged once) + combined agg ---
    gemm_fused<DHID, true><<<(NODES + 63) / 64, 256, 0, stream>>>(
        x, rout, W1, m_all);
    agg_kernel<DHID, true><<<NODES / 16, 256, 0, stream>>>(
        m_all, rowptr, rel01, csr, rin, b1, nullptr, h);

    // --- layer 2: fused 3-rel GEMM (h bf16 staged once) + combined agg ---
    gemm_fused<DOUT, false><<<(NODES + 63) / 64, 256, 0, stream>>>(
        h, rout, W2, m_all);
    agg_kernel<DOUT, false><<<NODES / 16, 256, 0, stream>>>(
        m_all, rowptr, rel01, csr, rin, b2, out, nullptr);
}